// Round 6
// baseline (659.922 us; speedup 1.0000x reference)
//
#include <hip/hip_runtime.h>
#include <stdint.h>
#include <type_traits>

typedef unsigned short u16;
typedef unsigned int u32;
typedef __bf16 bf16x8 __attribute__((ext_vector_type(8)));
typedef float f32x4 __attribute__((ext_vector_type(4)));

#define S_LEN 2048
#define DMODEL 2304
#define DFF 9216
#define NHQ 8
#define NHKV 4
#define HDIM 256
#define SWIN 1024

template <int N> using IC = std::integral_constant<int, N>;

__device__ __forceinline__ u16 f2bf(float f) {
  u32 u = __float_as_uint(f);
  u = (u + 0x7FFFu + ((u >> 16) & 1)) >> 16;
  return (u16)u;
}
__device__ __forceinline__ float bf2f(u16 h) {
  return __uint_as_float(((u32)h) << 16);
}

__device__ __forceinline__ void gload_lds16(const void* g, void* l) {
  __builtin_amdgcn_global_load_lds((const __attribute__((address_space(1))) u32*)g,
                                   (__attribute__((address_space(3))) u32*)l, 16, 0, 0);
}

template <int N>
__device__ __forceinline__ void wait_vmcnt() {
  if constexpr (N == 0) asm volatile("s_waitcnt vmcnt(0)" ::: "memory");
  else if constexpr (N == 4) asm volatile("s_waitcnt vmcnt(4)" ::: "memory");
  else if constexpr (N == 5) asm volatile("s_waitcnt vmcnt(5)" ::: "memory");
  else if constexpr (N == 6) asm volatile("s_waitcnt vmcnt(6)" ::: "memory");
  else if constexpr (N == 8) asm volatile("s_waitcnt vmcnt(8)" ::: "memory");
}

// inf-safe tanh-gelu
__device__ __forceinline__ float gelu_t(float x) {
  float u = 0.7978845608f * (x + 0.044715f * x * x * x);
  float e = __expf(2.f * u);
  float t = 1.f - 2.f / (e + 1.f);
  return 0.5f * x * (1.f + t);
}

// ---- LDS-free direct transpose+convert, hosted as extra blocks on other
// launches. Tile = 32k x 128n. Reads: for fixed (ch,j), 16-lane clusters of
// consecutive n -> 64B coalesced transactions. Writes: 4 consecutive threads
// cover one n-row's 4x16B -> 64B-grouped. 16 loads hoisted for latency.
template <int NT>
__device__ __forceinline__ void direct_transpose(
    const float* __restrict__ in, u16* __restrict__ out, int K, int N, int t, int nk) {
  const int k0 = (t % nk) * 32, n0 = (t / nk) * 128;
  const int tid = (int)threadIdx.x;
  const int nn = tid >> 2, ch = tid & 3;
  const int kb = k0 + ch * 8;
  constexpr int NP = (NT == 256) ? 2 : 1;
  float x[NP][8];
#pragma unroll
  for (int p = 0; p < NP; ++p) {
    const int n = n0 + nn + p * (NT / 4);
#pragma unroll
    for (int j = 0; j < 8; ++j) x[p][j] = in[(size_t)(kb + j) * N + n];
  }
#pragma unroll
  for (int p = 0; p < NP; ++p) {
    const int n = n0 + nn + p * (NT / 4);
    u32 w[4];
#pragma unroll
    for (int jj = 0; jj < 4; ++jj)
      w[jj] = (u32)f2bf(x[p][2 * jj]) | ((u32)f2bf(x[p][2 * jj + 1]) << 16);
    *(uint4*)&out[(size_t)n * K + kb] = make_uint4(w[0], w[1], w[2], w[3]);
  }
}

// -------- transpose + fp32->bf16 convert, 32k x 128n tiles, float4 reads ----
// (standalone: used for wq/wk/wv and the non-fused fallback path)
__global__ __launch_bounds__(256) void transpose_convert(
    const float* __restrict__ in, u16* __restrict__ out, int K, int N, int stride) {
  __shared__ float t[32][130];
  const int k0 = blockIdx.x * 32, n0 = blockIdx.y * 128;
  const int tx = threadIdx.x & 31, ty = threadIdx.x >> 5;  // ty 0..7
#pragma unroll
  for (int r = 0; r < 4; ++r) {
    const float4 v = *(const float4*)&in[(size_t)(k0 + ty + r * 8) * stride + n0 + 4 * tx];
    t[ty + r * 8][4 * tx + 0] = v.x;
    t[ty + r * 8][4 * tx + 1] = v.y;
    t[ty + r * 8][4 * tx + 2] = v.z;
    t[ty + r * 8][4 * tx + 3] = v.w;
  }
  __syncthreads();
  const int kk = threadIdx.x & 15, nn = threadIdx.x >> 4;  // kk 0..15, nn 0..15
#pragma unroll
  for (int r = 0; r < 8; ++r) {
    const int n = nn + r * 16;
    const u32 p = (u32)f2bf(t[2 * kk][n]) | ((u32)f2bf(t[2 * kk + 1][n]) << 16);
    *(u32*)&out[(size_t)(n0 + n) * K + k0 + 2 * kk] = p;
  }
}

// V pack: qkvf [S][4096] (cols 3072+) -> vtile[kvh][S/32][256 d][32 k] bf16
__global__ __launch_bounds__(256) void vpack_kernel(
    const float* __restrict__ qkvf, u16* __restrict__ vtile) {
  __shared__ float t[32][33];
  const int s0 = blockIdx.x * 32, d0 = blockIdx.y * 32, kvh = blockIdx.z;
  const int tx = threadIdx.x & 31, ty = threadIdx.x >> 5;
#pragma unroll
  for (int r = 0; r < 4; ++r)
    t[ty + r * 8][tx] = qkvf[(size_t)(s0 + ty + r * 8) * 4096 + 3072 + kvh * HDIM + d0 + tx];
  __syncthreads();
  const int kk = threadIdx.x & 15, nn = threadIdx.x >> 4;
#pragma unroll
  for (int r = 0; r < 2; ++r) {
    const int d = nn + r * 16;
    const u32 p = (u32)f2bf(t[2 * kk][d]) | ((u32)f2bf(t[2 * kk + 1][d]) << 16);
    *(u32*)&vtile[(((size_t)kvh * 64 + (s0 >> 5)) * 256 + d0 + d) * 32 + 2 * kk] = p;
  }
}

// ---------------- RMSNorm variants ----------------
__device__ __forceinline__ float block_sumsq(const float* xr, int D) {
  float ss = 0.f;
  for (int d = threadIdx.x; d < D; d += 256) { float v = xr[d]; ss += v * v; }
#pragma unroll
  for (int m = 1; m < 64; m <<= 1) ss += __shfl_xor(ss, m, 64);
  __shared__ float red[4];
  if ((threadIdx.x & 63) == 0) red[threadIdx.x >> 6] = ss;
  __syncthreads();
  return red[0] + red[1] + red[2] + red[3];
}

__global__ __launch_bounds__(256) void rmsnorm_bf16_kernel(
    const float* __restrict__ x, const float* __restrict__ w, u16* __restrict__ o) {
  const int row = blockIdx.x;
  const float* xr = x + (size_t)row * DMODEL;
  float tot = block_sumsq(xr, DMODEL);
  float inv = rsqrtf(tot / DMODEL + 1e-6f);
  u16* orow = o + (size_t)row * DMODEL;
  for (int d = threadIdx.x; d < DMODEL; d += 256)
    orow[d] = f2bf((1.f + w[d]) * (xr[d] * inv));
}

// fused: y = y0 + y1 (split-K partials); x = res + (1+w1)*rms(y);
//        xres = x;  hn = bf16((1+w2)*rms(x))
__global__ __launch_bounds__(256) void rms_add_rms_kernel(
    const float* __restrict__ y0, const float* __restrict__ y1,
    const float* __restrict__ w1,
    const float* __restrict__ res, const float* __restrict__ w2,
    float* __restrict__ xres, u16* __restrict__ hn) {
  const int row = blockIdx.x;
  const float* yr0 = y0 + (size_t)row * DMODEL;
  const float* yr1 = y1 + (size_t)row * DMODEL;
  const float* rr = res + (size_t)row * DMODEL;
  __shared__ float red[2][4];
  float yv[9];
  float ss = 0.f;
#pragma unroll
  for (int e = 0; e < 9; ++e) {
    const int d = threadIdx.x + e * 256;
    yv[e] = yr0[d] + yr1[d];
    ss += yv[e] * yv[e];
  }
#pragma unroll
  for (int m = 1; m < 64; m <<= 1) ss += __shfl_xor(ss, m, 64);
  if ((threadIdx.x & 63) == 0) red[0][threadIdx.x >> 6] = ss;
  __syncthreads();
  const float inv1 = rsqrtf((red[0][0] + red[0][1] + red[0][2] + red[0][3]) / DMODEL + 1e-6f);
  float* xr = xres + (size_t)row * DMODEL;
  float xv[9];
  float ss2 = 0.f;
#pragma unroll
  for (int e = 0; e < 9; ++e) {
    const int d = threadIdx.x + e * 256;
    float x = rr[d] + (1.f + w1[d]) * (yv[e] * inv1);
    xv[e] = x;
    xr[d] = x;
    ss2 += x * x;
  }
#pragma unroll
  for (int m = 1; m < 64; m <<= 1) ss2 += __shfl_xor(ss2, m, 64);
  if ((threadIdx.x & 63) == 0) red[1][threadIdx.x >> 6] = ss2;
  __syncthreads();
  const float inv2 = rsqrtf((red[1][0] + red[1][1] + red[1][2] + red[1][3]) / DMODEL + 1e-6f);
  u16* hr = hn + (size_t)row * DMODEL;
#pragma unroll
  for (int e = 0; e < 9; ++e) {
    const int d = threadIdx.x + e * 256;
    hr[d] = f2bf((1.f + w2[d]) * (xv[e] * inv2));
  }
}

// 8-way split-K reduce (bf16 partials) + RMSNorm + residual add (final out)
__global__ __launch_bounds__(256) void reduce8_rms_add_kernel(
    const u16* __restrict__ p, const float* __restrict__ w,
    const float* __restrict__ res, float* __restrict__ o) {
  const int row = blockIdx.x;
  const size_t PS = (size_t)S_LEN * DMODEL;
  const u16* pr = p + (size_t)row * DMODEL;
  float y[9];
  float ss = 0.f;
#pragma unroll
  for (int e = 0; e < 9; ++e) {
    const int d = threadIdx.x + e * 256;
    float v = 0.f;
#pragma unroll
    for (int k = 0; k < 8; ++k) v += bf2f(pr[d + k * PS]);
    y[e] = v;
    ss += v * v;
  }
#pragma unroll
  for (int m = 1; m < 64; m <<= 1) ss += __shfl_xor(ss, m, 64);
  __shared__ float red[4];
  if ((threadIdx.x & 63) == 0) red[threadIdx.x >> 6] = ss;
  __syncthreads();
  const float tot = red[0] + red[1] + red[2] + red[3];
  const float inv = rsqrtf(tot / DMODEL + 1e-6f);
  const float* rr = res + (size_t)row * DMODEL;
  float* orow = o + (size_t)row * DMODEL;
#pragma unroll
  for (int e = 0; e < 9; ++e) {
    const int d = threadIdx.x + e * 256;
    orow[d] = rr[d] + (1.f + w[d]) * (y[e] * inv);
  }
}

// ---------------- RoPE (q,k) fp32 -> bf16; K repacked per-head ----------------
__global__ void rope_kernel(const float* __restrict__ qkv, const int* __restrict__ pos,
                            u16* __restrict__ qb, u16* __restrict__ kt) {
  const int s = blockIdx.x;
  const int t = threadIdx.x;  // 0..127
  float p = (float)pos[s];
  float inv = powf(10000.f, -(float)(2 * t) / (float)HDIM);
  float f = p * inv;
  float cs = cosf(f), sn = sinf(f);
  const float* row = qkv + (size_t)s * 4096;
  u16* qr = qb + (size_t)s * (NHQ * HDIM);
#pragma unroll
  for (int h = 0; h < NHQ; ++h) {
    float x1 = row[h * HDIM + t], x2 = row[h * HDIM + t + 128];
    qr[h * HDIM + t] = f2bf(x1 * cs - x2 * sn);
    qr[h * HDIM + t + 128] = f2bf(x2 * cs + x1 * sn);
  }
#pragma unroll
  for (int h = 0; h < NHKV; ++h) {
    u16* kr = kt + ((size_t)h * S_LEN + s) * HDIM;
    float x1 = row[2048 + h * HDIM + t], x2 = row[2048 + h * HDIM + t + 128];
    kr[t] = f2bf(x1 * cs - x2 * sn);
    kr[t + 128] = f2bf(x2 * cs + x1 * sn);
  }
}

// ---------------- pipelined bf16 GEMM, C = A[M,Klen] * Bt[N,Klen]^T --------
// MODE: 0 = fp32 out (+kz), 1 = bf16 out (+kz), 2 = bf16 fused gelu(gptr)*acc,
//       4 = DUAL: G = A*Bt^T, U = A*Bt2^T, epilogue writes bf16 gelu(G)*U.
// BUFS: 2 = r0-proven drain double buffer {stage; compute; vmcnt0; barrier}.
//       3 = r2-verified triple-buffer rotation (fallback path only).
// Blocks with blockIdx.x >= ggrid run a hosted LDS-free transpose
// (tin -> toutT, tile geometry tK/tN/tnk) -- independent work co-resident
// with the GEMM to hide BW-bound transposes under compute-bound GEMM time.
// 8 waves (2x4), wave tile 64 x BN/4.
template <int BN, int MODE, int BUFS>
__global__ __launch_bounds__(512) void gemm_pipe(
    const u16* __restrict__ A, const u16* __restrict__ Bt, const u16* __restrict__ Bt2,
    void* __restrict__ Cv, void* __restrict__ Cv2,
    int M, int N, int Klen, int LDK, int ntn, int n1,
    const u16* __restrict__ gptr,
    int ggrid, const float* __restrict__ tin, u16* __restrict__ toutT,
    int tK, int tN, int tnk) {
  if ((int)blockIdx.x >= ggrid) {
    direct_transpose<512>(tin, toutT, tK, tN, (int)blockIdx.x - ggrid, tnk);
    return;
  }
  constexpr bool DUAL = (MODE == 4);
  constexpr int CH_B = BN / 8;
  constexpr int CH_TOT = 16 + (DUAL ? 2 * CH_B : CH_B);
  constexpr int LPW = CH_TOT / 8;
  constexpr int TILE = CH_TOT * 512;
  constexpr int NFR = BN / 64;
  __shared__ __align__(16) u16 smem[BUFS * TILE];

  const int tid = threadIdx.x;
  const int lane = tid & 63, wave = tid >> 6;
  const int wr = wave >> 2, wc = wave & 3;
  const int l15 = lane & 15, l16 = lane >> 4;

  const int MB = M >> 7;
  const int nwg = ggrid;
  const int orig = blockIdx.x;
  const int q = nwg >> 3, r = nwg & 7, xcd = orig & 7, lidx = orig >> 3;
  const int wg = (xcd < r ? xcd * (q + 1) : r * (q + 1) + (xcd - r) * q) + lidx;
  const int tiles = MB * ntn;
  const int kz = wg / tiles, wgt = wg % tiles;
  const int bm = wgt % MB, bn = wgt / MB;
  const bool side2 = !DUAL && bn >= n1;
  const int bnl = side2 ? bn - n1 : bn;
  const u16* Bp = side2 ? Bt2 : Bt;

  const u16* Az = A + (size_t)kz * Klen;
  const u16* Bz = Bp + (size_t)kz * Klen;
  const int NT = Klen >> 6;

  const u16* src[LPW];
  const int swz = (((lane & 7) ^ (lane >> 3)) * 8);
#pragma unroll
  for (int i = 0; i < LPW; ++i) {
    const int c = wave * LPW + i;
    if (c < 16) src[i] = Az + (size_t)(bm * 128 + c * 8 + (lane >> 3)) * LDK + swz;
    else if (!DUAL || c < 16 + CH_B)
      src[i] = Bz + (size_t)(bnl * BN + (c - 16) * 8 + (lane >> 3)) * LDK + swz;
    else
      src[i] = Bt2 + (size_t)kz * Klen + (size_t)(bnl * BN + (c - 16 - CH_B) * 8 + (lane >> 3)) * LDK + swz;
  }
  const int dst0 = wave * LPW * 512 + lane * 8;

  auto STAGE = [&](int buf, int kt) {
    u16* base = smem + buf * TILE + dst0;
    const size_t ko = (size_t)kt * 64;
#pragma unroll
    for (int i = 0; i < LPW; ++i) gload_lds16(src[i] + ko, base + i * 512);
  };

  f32x4 acc[4][NFR];
  f32x4 acc2[DUAL ? 4 : 1][DUAL ? NFR : 1];
#pragma unroll
  for (int m = 0; m < 4; ++m)
#pragma unroll
    for (int n = 0; n < NFR; ++n) {
      acc[m][n] = f32x4{0.f, 0.f, 0.f, 0.f};
      if constexpr (DUAL) acc2[m][n] = f32x4{0.f, 0.f, 0.f, 0.f};
    }

  bf16x8 a[2][4], b[2][NFR];
  bf16x8 u[DUAL ? 2 : 1][DUAL ? NFR : 1];

  auto READK = [&](auto kkc, int buf) {
    constexpr int kk = decltype(kkc)::value;
    const u16* Ab = smem + buf * TILE;
    const u16* Bb = Ab + 16 * 512;
    const u16* Ub = Ab + (16 + CH_B) * 512;
    const int cc = kk * 4 + l16;
#pragma unroll
    for (int m = 0; m < 4; ++m) {
      const int rr = wr * 64 + m * 16 + l15;
      a[kk][m] = *(const bf16x8*)&Ab[rr * 64 + ((cc ^ (rr & 7)) * 8)];
    }
#pragma unroll
    for (int n = 0; n < NFR; ++n) {
      const int rr = wc * (BN / 4) + n * 16 + l15;
      b[kk][n] = *(const bf16x8*)&Bb[rr * 64 + ((cc ^ (rr & 7)) * 8)];
      if constexpr (DUAL)
        u[kk][n] = *(const bf16x8*)&Ub[rr * 64 + ((cc ^ (rr & 7)) * 8)];
    }
  };

  auto MFMAK = [&](auto kkc) {
    constexpr int kk = decltype(kkc)::value;
    __builtin_amdgcn_s_setprio(1);
#pragma unroll
    for (int m = 0; m < 4; ++m)
#pragma unroll
      for (int n = 0; n < NFR; ++n)
        acc[m][n] = __builtin_amdgcn_mfma_f32_16x16x32_bf16(a[kk][m], b[kk][n], acc[m][n], 0, 0, 0);
    if constexpr (DUAL) {
#pragma unroll
      for (int m = 0; m < 4; ++m)
#pragma unroll
        for (int n = 0; n < NFR; ++n)
          acc2[m][n] = __builtin_amdgcn_mfma_f32_16x16x32_bf16(a[kk][m], u[kk][n], acc2[m][n], 0, 0, 0);
    }
    __builtin_amdgcn_s_setprio(0);
  };

  if constexpr (BUFS == 2) {
    // r0-proven schedule: stage next tile into OTHER buffer, compute, drain.
    STAGE(0, 0);
    wait_vmcnt<0>();
    __builtin_amdgcn_s_barrier();
    int cur = 0;
    for (int t = 0; t < NT; ++t) {
      if (t + 1 < NT) STAGE(cur ^ 1, t + 1);
      READK(IC<0>{}, cur);
      READK(IC<1>{}, cur);
      MFMAK(IC<0>{});
      MFMAK(IC<1>{});
      if (t + 1 < NT) { wait_vmcnt<0>(); __builtin_amdgcn_s_barrier(); }
      cur ^= 1;
    }
  } else {
    // 3-buf rotation (r2-verified): fallback path only.
    STAGE(0, 0);
    STAGE(1, 1);
    wait_vmcnt<0>();
    __builtin_amdgcn_s_barrier();
    READK(IC<0>{}, 0);
    int cur = 0;
    for (int t = 0; t < NT; ++t) {
      const int nxt = (cur == 2) ? 0 : cur + 1;
      const int fre = (nxt == 2) ? 0 : nxt + 1;
      if (t + 2 < NT) STAGE(fre, t + 2);
      READK(IC<1>{}, cur);
      MFMAK(IC<0>{});
      if (t + 1 < NT) READK(IC<0>{}, nxt);
      MFMAK(IC<1>{});
      if (t + 1 < NT) { wait_vmcnt<0>(); __builtin_amdgcn_s_barrier(); }
      cur = nxt;
    }
  }

  const int row0 = bm * 128 + wr * 64 + l16 * 4;
  const int col0 = bnl * BN + wc * (BN / 4) + l15;
  float* Cf = (float*)(side2 ? Cv2 : Cv) + (size_t)kz * M * N;
  u16* Cb = (u16*)(side2 ? Cv2 : Cv) + (size_t)kz * M * N;
#pragma unroll
  for (int m = 0; m < 4; ++m)
#pragma unroll
    for (int n = 0; n < NFR; ++n)
#pragma unroll
      for (int rr = 0; rr < 4; ++rr) {
        const size_t idx = (size_t)(row0 + m * 16 + rr) * N + col0 + n * 16;
        if (MODE == 0) Cf[idx] = acc[m][n][rr];
        else if (MODE == 1) Cb[idx] = f2bf(acc[m][n][rr]);
        else if (MODE == 2) ((u16*)Cv)[idx] = f2bf(gelu_t(bf2f(gptr[idx])) * acc[m][n][rr]);
        else if (MODE == 4) {
          if constexpr (DUAL)
            ((u16*)Cv)[idx] = f2bf(gelu_t(acc[m][n][rr]) * acc2[m][n][rr]);
        }
      }
}

// ---------------- flash attention: 4-wave / 64 q-rows, LDS-staged KV -------
// Blocks >= 256 host LDS-free transposes of {wo, wg, wu} (independent work;
// attn's 256 blocks leave >half the CUs free, so these run concurrently).
__global__ __launch_bounds__(256) void attn_kernel(
    const u16* __restrict__ qb, const u16* __restrict__ kt,
    const u16* __restrict__ vtile, const int* __restrict__ amask,
    u16* __restrict__ outp,
    const float* __restrict__ t0in, u16* __restrict__ t0out,
    const float* __restrict__ t1in, u16* __restrict__ t1out,
    const float* __restrict__ t2in, u16* __restrict__ t2out) {
  __shared__ __align__(16) u16 Ks[2][32 * 256];
  __shared__ __align__(16) u16 Vs[2][256 * 32];
  __shared__ __align__(16) u16 Ps[4][16 * 40];
  const int bid = blockIdx.x;
  if (bid >= 256) {
    int t = bid - 256;
    if (t < 1152)      direct_transpose<256>(t0in, t0out, 2048, 2304, t, 64);        // wo
    else if (t < 6336) direct_transpose<256>(t1in, t1out, 2304, 9216, t - 1152, 72); // wg
    else               direct_transpose<256>(t2in, t2out, 2304, 9216, t - 6336, 72); // wu
    return;
  }
  const int qh = bid & 7;          // head = XCD
  const int qblk = bid >> 3;
  const int kvh = qh >> 1;
  const int q0 = qblk * 64;
  const int tid = threadIdx.x, lane = tid & 63, wave = tid >> 6;
  const int qrow = q0 + wave * 16;
  const int l15 = lane & 15, l16 = lane >> 4;

  bf16x8 qf[8];
  {
    const u16* qp = qb + (size_t)(qrow + l15) * (NHQ * HDIM) + qh * HDIM + l16 * 8;
#pragma unroll
    for (int kc = 0; kc < 8; ++kc) qf[kc] = *(const bf16x8*)(qp + kc * 32);
  }
  f32x4 acc[16];
#pragma unroll
  for (int n = 0; n < 16; ++n) acc[n] = f32x4{0.f, 0.f, 0.f, 0.f};
  float mr[4] = {-1e30f, -1e30f, -1e30f, -1e30f};
  float sr[4] = {0.f, 0.f, 0.f, 0.f};

  int lo = q0 - (SWIN - 1); if (lo < 0) lo = 0; lo &= ~31;
  const int ntiles = ((q0 + 63 - lo) >> 5) + 1;

  const char* kbase = (const char*)(kt + (size_t)kvh * S_LEN * HDIM);
  const char* vbase = (const char*)(vtile + (size_t)kvh * 64 * 256 * 32);

  auto STAGEKV = [&](int buf, int key0) {
    const char* ksrc = kbase + (size_t)key0 * 512;
    const char* vsrc = vbase + (size_t)(key0 >> 5) * 16384;
#pragma unroll
    for (int i = 0; i < 4; ++i) {
      const int b = (wave * 4 + i) * 1024 + lane * 16;
      gload_lds16(ksrc + (b ^ (((b >> 9) & 7) << 4)), (char*)&Ks[buf][0] + (wave * 4 + i) * 1024);
    }
#pragma unroll
    for (int i = 0; i < 4; ++i) {
      const int b = (wave * 4 + i) * 1024 + lane * 16;
      gload_lds16(vsrc + (b ^ (((b >> 6) & 3) << 4)), (char*)&Vs[buf][0] + (wave * 4 + i) * 1024);
    }
  };

  STAGEKV(0, lo);
  wait_vmcnt<0>();
  __builtin_amdgcn_s_barrier();

  int cur = 0;
  for (int it = 0; it < ntiles; ++it) {
    const int key0 = lo + it * 32;
    const int am0 = amask[key0 + l15];
    const int am1 = amask[key0 + 16 + l15];
    if (it + 1 < ntiles) { STAGEKV(cur ^ 1, key0 + 32); wait_vmcnt<8>(); }
    else                 { wait_vmcnt<0>(); }
    __builtin_amdgcn_s_barrier();

    if (key0 <= qrow + 15 && key0 + 31 >= qrow - (SWIN - 1)) {
      f32x4 sc[2];
      sc[0] = f32x4{0.f, 0.f, 0.f, 0.f};
      sc[1] = f32x4{0.f, 0.f, 0.f, 0.f};
#pragma unroll
      for (int ct = 0; ct < 2; ++ct) {
        const int r = ct * 16 + l15;
#pragma unroll
        for (int kc = 0; kc < 8; ++kc) {
          const int byte = (r * 512 + kc * 64 + l16 * 16) ^ ((r & 7) << 4);
          bf16x8 kf = *(const bf16x8*)((const char*)&Ks[cur][0] + byte);
          sc[ct] = __builtin_amdgcn_mfma_f32_16x16x32_bf16(qf[kc], kf, sc[ct], 0, 0, 0);
        }
      }
      float pr[2][4];
#pragma unroll
      for (int ct = 0; ct < 2; ++ct) {
        const int j = key0 + ct * 16 + l15;
        const bool jok = (ct ? am1 : am0) > 0;
#pragma unroll
        for (int r = 0; r < 4; ++r) {
          const int i = qrow + l16 * 4 + r;
          const bool ok = jok && (j <= i) && (i - j < SWIN);
          pr[ct][r] = ok ? sc[ct][r] * 0.0625f : -1e30f;
        }
      }
      float resc[4];
#pragma unroll
      for (int r = 0; r < 4; ++r) {
        float mx = fmaxf(pr[0][r], pr[1][r]);
#pragma unroll
        for (int mm = 1; mm < 16; mm <<= 1) mx = fmaxf(mx, __shfl_xor(mx, mm, 64));
        const float mnew = fmaxf(mr[r], mx);
        const float rs = __expf(mr[r] - mnew);
        mr[r] = mnew;
        float p0 = __expf(pr[0][r] - mnew);
        float p1 = __expf(pr[1][r] - mnew);
        pr[0][r] = p0; pr[1][r] = p1;
        float sm = p0 + p1;
#pragma unroll
        for (int mm = 1; mm < 16; mm <<= 1) sm += __shfl_xor(sm, mm, 64);
        sr[r] = sr[r] * rs + sm;
        resc[r] = rs;
      }
#pragma unroll
      for (int n = 0; n < 16; ++n)
#pragma unroll
        for (int r = 0; r < 4; ++r) acc[n][r] *= resc[r];
      u16* P = &Ps[wave][0];
#pragma unroll
      for (int ct = 0; ct < 2; ++ct)
#pragma unroll
        for (int r = 0; r < 4; ++r)
          P[(l16 * 4 + r) * 40 + ct * 16 + l15] = f2bf(pr[ct][r]);
      bf16x8 pa = *(const bf16x8*)&P[l15 * 40 + l16 * 8];
#pragma unroll
      for (int n = 0; n < 16; ++n) {
        const int d = n * 16 + l15;
        const int byte = (d * 64 + l16 * 16) ^ ((d & 3) << 4);
        bf16x8 vf = *(const bf16x8*)((const char*)&Vs[cur][0] + byte);
        acc[n] = __builtin_amdgcn_mfma_f32_16x16x32_bf16(pa, vf, acc[n], 0, 0, 0);
      }
    }
    __builtin_amdgcn_s_barrier();
    cur ^= 1;
  }
#pragma unroll
  for (int n = 0; n < 16; ++n)
#pragma unroll
    for (int r = 0; r < 4; ++r) {
      const int i = qrow + l16 * 4 + r;
      outp[(size_t)i * (NHQ * HDIM) + qh * HDIM + n * 16 + l15] = f2bf(acc[n][r] / sr[r]);
    }
}

// ---------------- gelu(tanh) * up (fallback path only) ----------------
__global__ void gelu_mul_kernel(const u16* __restrict__ g, const u16* __restrict__ u,
                                u16* __restrict__ o, int n8) {
  const int idx0 = blockIdx.x * blockDim.x + threadIdx.x;
  const int stride = gridDim.x * blockDim.x;
  for (int i = idx0; i < n8; i += stride) {
    uint4 gv = ((const uint4*)g)[i];
    uint4 uv = ((const uint4*)u)[i];
    u32 gg[4] = {gv.x, gv.y, gv.z, gv.w};
    u32 uu[4] = {uv.x, uv.y, uv.z, uv.w};
    u32 ow[4];
#pragma unroll
    for (int w = 0; w < 4; ++w) {
      float x0 = bf2f((u16)(gg[w] & 0xffff)), x1 = bf2f((u16)(gg[w] >> 16));
      float y0 = bf2f((u16)(uu[w] & 0xffff)), y1 = bf2f((u16)(uu[w] >> 16));
      ow[w] = (u32)f2bf(gelu_t(x0) * y0) | ((u32)f2bf(gelu_t(x1) * y1) << 16);
    }
    ((uint4*)o)[i] = make_uint4(ow[0], ow[1], ow[2], ow[3]);
  }
}

extern "C" void kernel_launch(void* const* d_in, const int* in_sizes, int n_in,
                              void* d_out, int out_size, void* d_ws, size_t ws_size,
                              hipStream_t stream) {
  const float* hidden = (const float*)d_in[0];
  const int*   amask  = (const int*)d_in[1];
  const int*   pos    = (const int*)d_in[2];
  const float* wq     = (const float*)d_in[3];
  const float* wk     = (const float*)d_in[4];
  const float* wv     = (const float*)d_in[5];
  const float* wo     = (const float*)d_in[6];
  const float* wg     = (const float*)d_in[7];
  const float* wu     = (const float*)d_in[8];
  const float* wd     = (const float*)d_in[9];
  const float* ln_in  = (const float*)d_in[10];
  const float* ln_pa  = (const float*)d_in[11];
  const float* ln_pf  = (const float*)d_in[12];
  const float* ln_po  = (const float*)d_in[13];
  float* out = (float*)d_out;

  char* ws = (char*)d_ws;
  size_t off = 0;
  auto alloc = [&](size_t b) { char* p = ws + off; off += (b + 255) & ~(size_t)255; return p; };
  u16*   WT    = (u16*)alloc((size_t)DFF * DMODEL * 2);
  u16*   hnorm = (u16*)alloc((size_t)S_LEN * DMODEL * 2);
  char*  big0  = alloc((size_t)S_LEN * DFF * 2);
  u16*   qb    = (u16*)alloc((size_t)S_LEN * NHQ * HDIM * 2);
  u16*   ktb   = (u16*)alloc((size_t)NHKV * S_LEN * HDIM * 2);
  u16*   vtile = (u16*)alloc((size_t)NHKV * 64 * 256 * 32 * 2);
  u16*   attn  = (u16*)alloc((size_t)S_LEN * NHQ * HDIM * 2);
  float* f32t  = (float*)alloc((size_t)S_LEN * DMODEL * 4);
  float* xres  = (float*)alloc((size_t)S_LEN * DMODEL * 4);
  u16*   gbuf  = (u16*)alloc((size_t)S_LEN * DFF * 2);
  u16*   ubuf  = (u16*)alloc((size_t)S_LEN * DFF * 2);
  u16*   WTU   = (u16*)alloc((size_t)DFF * DMODEL * 2);
  const bool fused_gu = (off <= ws_size);
  (void)n_in; (void)in_sizes; (void)out_size; (void)ubuf;
  float* qkvf = (float*)big0;
  u16*   ggu  = (u16*)big0;
  float* opart = (float*)big0;  // o-proj split-K2 fp32 partials (37.7MB)
  u16*   part = gbuf;           // 8x bf16 down partials = exactly gbuf+ubuf
  u16*   WTO  = (u16*)f32t;     // wo^T (9.4MB, hosted on attn launch)
  u16*   WTG  = gbuf;           // wg^T (42.5MB, spills into ubuf; free til step 12)
  const size_t PS = (size_t)S_LEN * DMODEL;

  const dim3 B256(256), B128(128), B512(512);

  // 1. h = rms(hidden, ln_in)
  rmsnorm_bf16_kernel<<<dim3(S_LEN), B256, 0, stream>>>(hidden, ln_in, hnorm);
  // 2. W_{q,k,v}^T  (32k x 128n float4 tiles)
  transpose_convert<<<dim3(DMODEL / 32, 2048 / 128), B256, 0, stream>>>(wq, WT, DMODEL, 2048, 2048);
  transpose_convert<<<dim3(DMODEL / 32, 1024 / 128), B256, 0, stream>>>(wk, WT + (size_t)2048 * DMODEL, DMODEL, 1024, 1024);
  transpose_convert<<<dim3(DMODEL / 32, 1024 / 128), B256, 0, stream>>>(wv, WT + (size_t)3072 * DMODEL, DMODEL, 1024, 1024);
  // 3. qkv = h @ [wq|wk|wv]  (BN=128 2-buf: grid 512 = 1.0 round @2blk/CU)
  gemm_pipe<128, 0, 2><<<dim3(512), B512, 0, stream>>>(hnorm, WT, WT, qkvf, qkvf, S_LEN, 4096, DMODEL, DMODEL, 32, 32, nullptr, 512, nullptr, nullptr, 1, 1, 1);
  // 4. RoPE (writes q + per-head-packed K)
  rope_kernel<<<dim3(S_LEN), B128, 0, stream>>>(qkvf, pos, qb, ktb);
  // 5. V tiles
  vpack_kernel<<<dim3(S_LEN / 32, HDIM / 32, NHKV), B256, 0, stream>>>(qkvf, vtile);

  if (fused_gu) {
    // 6. attention + hosted {wo,wg,wu} transposes (attn uses ~half the CUs;
    //    transpose blocks backfill and run concurrently)
    attn_kernel<<<dim3(256 + 1152 + 5184 + 5184), B256, 0, stream>>>(
        qb, ktb, vtile, amask, attn, wo, WTO, wg, WTG, wu, WTU);
    // 7. o partials = attn @ wo^T + hosted wd transpose -> WT (free since qkv)
    gemm_pipe<192, 0, 2><<<dim3(384 + 5184), B512, 0, stream>>>(
        attn, WTO, WTO, opart, opart, S_LEN, DMODEL, 1024, 2048, 12, 12, nullptr,
        384, wd, WT, 9216, 2304, 288);
    // 8+9. x = hidden + rms(sum o-partials); h2 = rms(x)  (fused, one pass)
    rms_add_rms_kernel<<<dim3(S_LEN), B256, 0, stream>>>(opart, opart + PS, ln_pa, hidden, ln_pf, xres, hnorm);
    // 10+11. DUAL gate+up: ggu = gelu(h@wg)*(h@wu)  (BN=192 2-buf, 3 rounds)
    gemm_pipe<192, 4, 2><<<dim3(768), B512, 0, stream>>>(
        hnorm, WTG, WTU, ggu, nullptr, S_LEN, DFF, DMODEL, DMODEL, 48, 48, nullptr,
        768, nullptr, nullptr, 1, 1, 1);
    // 12. ffn bf16 partials = ggu @ wd^T (split-K=8: grid 1536; overwrites WTG)
    gemm_pipe<192, 1, 2><<<dim3(1536), B512, 0, stream>>>(
        ggu, WT, WT, part, part, S_LEN, DMODEL, DFF / 8, DFF, 12, 12, nullptr,
        1536, nullptr, nullptr, 1, 1, 1);
  } else {
    // fallback: fully sequential original pipeline
    attn_kernel<<<dim3(256), B256, 0, stream>>>(qb, ktb, vtile, amask, attn,
                                                nullptr, nullptr, nullptr, nullptr, nullptr, nullptr);
    transpose_convert<<<dim3(2048 / 32, DMODEL / 128), B256, 0, stream>>>(wo, WT, 2048, DMODEL, DMODEL);
    gemm_pipe<192, 0, 2><<<dim3(384), B512, 0, stream>>>(attn, WT, WT, opart, opart, S_LEN, DMODEL, 1024, 2048, 12, 12, nullptr, 384, nullptr, nullptr, 1, 1, 1);
    rms_add_rms_kernel<<<dim3(S_LEN), B256, 0, stream>>>(opart, opart + PS, ln_pa, hidden, ln_pf, xres, hnorm);
    transpose_convert<<<dim3(DMODEL / 32, DFF / 128), B256, 0, stream>>>(wg, WT, DMODEL, DFF, DFF);
    gemm_pipe<192, 1, 3><<<dim3(768), B512, 0, stream>>>(hnorm, WT, WT, gbuf, gbuf, S_LEN, DFF, DMODEL, DMODEL, 48, 48, nullptr, 768, nullptr, nullptr, 1, 1, 1);
    transpose_convert<<<dim3(DMODEL / 32, DFF / 128), B256, 0, stream>>>(wu, WT, DMODEL, DFF, DFF);
    gemm_pipe<192, 2, 3><<<dim3(768), B512, 0, stream>>>(hnorm, WT, WT, ggu, ggu, S_LEN, DFF, DMODEL, DMODEL, 48, 48, gbuf, 768, nullptr, nullptr, 1, 1, 1);
    transpose_convert<<<dim3(DFF / 32, DMODEL / 128), B256, 0, stream>>>(wd, WT, DFF, DMODEL, DMODEL);
    gemm_pipe<192, 1, 2><<<dim3(1536), B512, 0, stream>>>(ggu, WT, WT, part, part, S_LEN, DMODEL, DFF / 8, DFF, 12, 12, nullptr, 1536, nullptr, nullptr, 1, 1, 1);
  }
  // 13. out = x + rms(sum of 8 bf16 partials)
  reduce8_rms_add_kernel<<<dim3(S_LEN), B256, 0, stream>>>(part, ln_po, xres, out);
}

// Round 7
// 578.004 us; speedup vs baseline: 1.1417x; 1.1417x over previous
//
#include <hip/hip_runtime.h>
#include <stdint.h>
#include <type_traits>

typedef unsigned short u16;
typedef unsigned int u32;
typedef __bf16 bf16x8 __attribute__((ext_vector_type(8)));
typedef float f32x4 __attribute__((ext_vector_type(4)));

#define S_LEN 2048
#define DMODEL 2304
#define DFF 9216
#define NHQ 8
#define NHKV 4
#define HDIM 256
#define SWIN 1024

template <int N> using IC = std::integral_constant<int, N>;

__device__ __forceinline__ u16 f2bf(float f) {
  u32 u = __float_as_uint(f);
  u = (u + 0x7FFFu + ((u >> 16) & 1)) >> 16;
  return (u16)u;
}
__device__ __forceinline__ float bf2f(u16 h) {
  return __uint_as_float(((u32)h) << 16);
}

__device__ __forceinline__ void gload_lds16(const void* g, void* l) {
  __builtin_amdgcn_global_load_lds((const __attribute__((address_space(1))) u32*)g,
                                   (__attribute__((address_space(3))) u32*)l, 16, 0, 0);
}

template <int N>
__device__ __forceinline__ void wait_vmcnt() {
  if constexpr (N == 0) asm volatile("s_waitcnt vmcnt(0)" ::: "memory");
  else if constexpr (N == 4) asm volatile("s_waitcnt vmcnt(4)" ::: "memory");
  else if constexpr (N == 5) asm volatile("s_waitcnt vmcnt(5)" ::: "memory");
  else if constexpr (N == 6) asm volatile("s_waitcnt vmcnt(6)" ::: "memory");
  else if constexpr (N == 8) asm volatile("s_waitcnt vmcnt(8)" ::: "memory");
}

// inf-safe tanh-gelu
__device__ __forceinline__ float gelu_t(float x) {
  float u = 0.7978845608f * (x + 0.044715f * x * x * x);
  float e = __expf(2.f * u);
  float t = 1.f - 2.f / (e + 1.f);
  return 0.5f * x * (1.f + t);
}

// -------- transpose + fp32->bf16 convert, 32k x 128n tiles, float4 reads ----
__global__ __launch_bounds__(256) void transpose_convert(
    const float* __restrict__ in, u16* __restrict__ out, int K, int N, int stride) {
  __shared__ float t[32][130];
  const int k0 = blockIdx.x * 32, n0 = blockIdx.y * 128;
  const int tx = threadIdx.x & 31, ty = threadIdx.x >> 5;  // ty 0..7
#pragma unroll
  for (int r = 0; r < 4; ++r) {
    const float4 v = *(const float4*)&in[(size_t)(k0 + ty + r * 8) * stride + n0 + 4 * tx];
    t[ty + r * 8][4 * tx + 0] = v.x;
    t[ty + r * 8][4 * tx + 1] = v.y;
    t[ty + r * 8][4 * tx + 2] = v.z;
    t[ty + r * 8][4 * tx + 3] = v.w;
  }
  __syncthreads();
  const int kk = threadIdx.x & 15, nn = threadIdx.x >> 4;  // kk 0..15, nn 0..15
#pragma unroll
  for (int r = 0; r < 8; ++r) {
    const int n = nn + r * 16;
    const u32 p = (u32)f2bf(t[2 * kk][n]) | ((u32)f2bf(t[2 * kk + 1][n]) << 16);
    *(u32*)&out[(size_t)(n0 + n) * K + k0 + 2 * kk] = p;
  }
}

// merged wq|wk|wv transpose: logical out rows [0,2048)=wq^T, [2048,3072)=wk^T,
// [3072,4096)=wv^T; one launch instead of three.
__global__ __launch_bounds__(256) void transpose_qkv_kernel(
    const float* __restrict__ wq, const float* __restrict__ wk,
    const float* __restrict__ wv, u16* __restrict__ out) {
  const int k0 = blockIdx.x * 32;     // K = 2304
  const int n0g = blockIdx.y * 128;   // logical N = 4096
  const float* in; int n0, N;
  if (n0g < 2048)      { in = wq; n0 = n0g;        N = 2048; }
  else if (n0g < 3072) { in = wk; n0 = n0g - 2048; N = 1024; }
  else                 { in = wv; n0 = n0g - 3072; N = 1024; }
  __shared__ float t[32][130];
  const int tx = threadIdx.x & 31, ty = threadIdx.x >> 5;
#pragma unroll
  for (int r = 0; r < 4; ++r) {
    const float4 v = *(const float4*)&in[(size_t)(k0 + ty + r * 8) * N + n0 + 4 * tx];
    t[ty + r * 8][4 * tx + 0] = v.x;
    t[ty + r * 8][4 * tx + 1] = v.y;
    t[ty + r * 8][4 * tx + 2] = v.z;
    t[ty + r * 8][4 * tx + 3] = v.w;
  }
  __syncthreads();
  const int kk = threadIdx.x & 15, nn = threadIdx.x >> 4;
#pragma unroll
  for (int r = 0; r < 8; ++r) {
    const int n = nn + r * 16;
    const u32 p = (u32)f2bf(t[2 * kk][n]) | ((u32)f2bf(t[2 * kk + 1][n]) << 16);
    *(u32*)&out[(size_t)(n0g + n) * DMODEL + k0 + 2 * kk] = p;
  }
}

// V pack: qkvf [S][4096] (cols 3072+) -> vtile[kvh][S/32][256 d][32 k] bf16
__global__ __launch_bounds__(256) void vpack_kernel(
    const float* __restrict__ qkvf, u16* __restrict__ vtile) {
  __shared__ float t[32][33];
  const int s0 = blockIdx.x * 32, d0 = blockIdx.y * 32, kvh = blockIdx.z;
  const int tx = threadIdx.x & 31, ty = threadIdx.x >> 5;
#pragma unroll
  for (int r = 0; r < 4; ++r)
    t[ty + r * 8][tx] = qkvf[(size_t)(s0 + ty + r * 8) * 4096 + 3072 + kvh * HDIM + d0 + tx];
  __syncthreads();
  const int kk = threadIdx.x & 15, nn = threadIdx.x >> 4;
#pragma unroll
  for (int r = 0; r < 2; ++r) {
    const int d = nn + r * 16;
    const u32 p = (u32)f2bf(t[2 * kk][d]) | ((u32)f2bf(t[2 * kk + 1][d]) << 16);
    *(u32*)&vtile[(((size_t)kvh * 64 + (s0 >> 5)) * 256 + d0 + d) * 32 + 2 * kk] = p;
  }
}

// ---------------- RMSNorm variants ----------------
__device__ __forceinline__ float block_sumsq(const float* xr, int D) {
  float ss = 0.f;
  for (int d = threadIdx.x; d < D; d += 256) { float v = xr[d]; ss += v * v; }
#pragma unroll
  for (int m = 1; m < 64; m <<= 1) ss += __shfl_xor(ss, m, 64);
  __shared__ float red[4];
  if ((threadIdx.x & 63) == 0) red[threadIdx.x >> 6] = ss;
  __syncthreads();
  return red[0] + red[1] + red[2] + red[3];
}

__global__ __launch_bounds__(256) void rmsnorm_bf16_kernel(
    const float* __restrict__ x, const float* __restrict__ w, u16* __restrict__ o) {
  const int row = blockIdx.x;
  const float* xr = x + (size_t)row * DMODEL;
  float tot = block_sumsq(xr, DMODEL);
  float inv = rsqrtf(tot / DMODEL + 1e-6f);
  u16* orow = o + (size_t)row * DMODEL;
  for (int d = threadIdx.x; d < DMODEL; d += 256)
    orow[d] = f2bf((1.f + w[d]) * (xr[d] * inv));
}

// fused: y = sum of 4 bf16 split-K partials; x = res + (1+w1)*rms(y);
//        xres = x;  hn = bf16((1+w2)*rms(x))
__global__ __launch_bounds__(256) void rms_add_rms_kernel(
    const u16* __restrict__ p, const float* __restrict__ w1,
    const float* __restrict__ res, const float* __restrict__ w2,
    float* __restrict__ xres, u16* __restrict__ hn) {
  const int row = blockIdx.x;
  const size_t PS = (size_t)S_LEN * DMODEL;
  const u16* pr = p + (size_t)row * DMODEL;
  const float* rr = res + (size_t)row * DMODEL;
  __shared__ float red[2][4];
  float yv[9];
  float ss = 0.f;
#pragma unroll
  for (int e = 0; e < 9; ++e) {
    const int d = threadIdx.x + e * 256;
    float v = 0.f;
#pragma unroll
    for (int k = 0; k < 4; ++k) v += bf2f(pr[d + k * PS]);
    yv[e] = v;
    ss += v * v;
  }
#pragma unroll
  for (int m = 1; m < 64; m <<= 1) ss += __shfl_xor(ss, m, 64);
  if ((threadIdx.x & 63) == 0) red[0][threadIdx.x >> 6] = ss;
  __syncthreads();
  const float inv1 = rsqrtf((red[0][0] + red[0][1] + red[0][2] + red[0][3]) / DMODEL + 1e-6f);
  float* xr = xres + (size_t)row * DMODEL;
  float xv[9];
  float ss2 = 0.f;
#pragma unroll
  for (int e = 0; e < 9; ++e) {
    const int d = threadIdx.x + e * 256;
    float x = rr[d] + (1.f + w1[d]) * (yv[e] * inv1);
    xv[e] = x;
    xr[d] = x;
    ss2 += x * x;
  }
#pragma unroll
  for (int m = 1; m < 64; m <<= 1) ss2 += __shfl_xor(ss2, m, 64);
  if ((threadIdx.x & 63) == 0) red[1][threadIdx.x >> 6] = ss2;
  __syncthreads();
  const float inv2 = rsqrtf((red[1][0] + red[1][1] + red[1][2] + red[1][3]) / DMODEL + 1e-6f);
  u16* hr = hn + (size_t)row * DMODEL;
#pragma unroll
  for (int e = 0; e < 9; ++e) {
    const int d = threadIdx.x + e * 256;
    hr[d] = f2bf((1.f + w2[d]) * (xv[e] * inv2));
  }
}

// 8-way split-K reduce (bf16 partials) + RMSNorm + residual add (final out)
__global__ __launch_bounds__(256) void reduce8_rms_add_kernel(
    const u16* __restrict__ p, const float* __restrict__ w,
    const float* __restrict__ res, float* __restrict__ o) {
  const int row = blockIdx.x;
  const size_t PS = (size_t)S_LEN * DMODEL;
  const u16* pr = p + (size_t)row * DMODEL;
  float y[9];
  float ss = 0.f;
#pragma unroll
  for (int e = 0; e < 9; ++e) {
    const int d = threadIdx.x + e * 256;
    float v = 0.f;
#pragma unroll
    for (int k = 0; k < 8; ++k) v += bf2f(pr[d + k * PS]);
    y[e] = v;
    ss += v * v;
  }
#pragma unroll
  for (int m = 1; m < 64; m <<= 1) ss += __shfl_xor(ss, m, 64);
  __shared__ float red[4];
  if ((threadIdx.x & 63) == 0) red[threadIdx.x >> 6] = ss;
  __syncthreads();
  const float tot = red[0] + red[1] + red[2] + red[3];
  const float inv = rsqrtf(tot / DMODEL + 1e-6f);
  const float* rr = res + (size_t)row * DMODEL;
  float* orow = o + (size_t)row * DMODEL;
#pragma unroll
  for (int e = 0; e < 9; ++e) {
    const int d = threadIdx.x + e * 256;
    orow[d] = rr[d] + (1.f + w[d]) * (y[e] * inv);
  }
}

// ---------------- RoPE (q,k) fp32 -> bf16; K repacked per-head ----------------
__global__ void rope_kernel(const float* __restrict__ qkv, const int* __restrict__ pos,
                            u16* __restrict__ qb, u16* __restrict__ kt) {
  const int s = blockIdx.x;
  const int t = threadIdx.x;  // 0..127
  float p = (float)pos[s];
  float inv = powf(10000.f, -(float)(2 * t) / (float)HDIM);
  float f = p * inv;
  float cs = cosf(f), sn = sinf(f);
  const float* row = qkv + (size_t)s * 4096;
  u16* qr = qb + (size_t)s * (NHQ * HDIM);
#pragma unroll
  for (int h = 0; h < NHQ; ++h) {
    float x1 = row[h * HDIM + t], x2 = row[h * HDIM + t + 128];
    qr[h * HDIM + t] = f2bf(x1 * cs - x2 * sn);
    qr[h * HDIM + t + 128] = f2bf(x2 * cs + x1 * sn);
  }
#pragma unroll
  for (int h = 0; h < NHKV; ++h) {
    u16* kr = kt + ((size_t)h * S_LEN + s) * HDIM;
    float x1 = row[2048 + h * HDIM + t], x2 = row[2048 + h * HDIM + t + 128];
    kr[t] = f2bf(x1 * cs - x2 * sn);
    kr[t + 128] = f2bf(x2 * cs + x1 * sn);
  }
}

// ---------------- pipelined bf16 GEMM, C = A[M,Klen] * Bt[N,Klen]^T --------
// MODE: 0 = fp32 out (+kz), 1 = bf16 out (+kz), 2 = bf16 fused gelu(gptr)*acc,
//       4 = DUAL: G = A*Bt^T, U = A*Bt2^T, epilogue writes bf16 gelu(G)*U.
// BUFS: 3 = counted-vmcnt triple buffer; 2 = issue-early drain double buffer.
// 8 waves (2x4), wave tile 64 x BN/4, all fragment loads hoisted.
template <int BN, int MODE, int BUFS>
__global__ __launch_bounds__(512) void gemm_pipe(
    const u16* __restrict__ A, const u16* __restrict__ Bt, const u16* __restrict__ Bt2,
    void* __restrict__ Cv, void* __restrict__ Cv2,
    int M, int N, int Klen, int LDK, int ntn, int n1,
    const u16* __restrict__ gptr) {
  constexpr bool DUAL = (MODE == 4);
  constexpr int CH_B = BN / 8;
  constexpr int CH_TOT = 16 + (DUAL ? 2 * CH_B : CH_B);
  constexpr int LPW = CH_TOT / 8;
  constexpr int TILE = CH_TOT * 512;
  constexpr int NFR = BN / 64;
  __shared__ __align__(16) u16 smem[BUFS * TILE];

  const int tid = threadIdx.x;
  const int lane = tid & 63, wave = tid >> 6;
  const int wr = wave >> 2, wc = wave & 3;
  const int l15 = lane & 15, l16 = lane >> 4;

  const int MB = M >> 7;
  const int nwg = gridDim.x;
  const int orig = blockIdx.x;
  const int q = nwg >> 3, r = nwg & 7, xcd = orig & 7, lidx = orig >> 3;
  const int wg = (xcd < r ? xcd * (q + 1) : r * (q + 1) + (xcd - r) * q) + lidx;
  const int tiles = MB * ntn;
  const int kz = wg / tiles, wgt = wg % tiles;
  const int bm = wgt % MB, bn = wgt / MB;
  const bool side2 = !DUAL && bn >= n1;
  const int bnl = side2 ? bn - n1 : bn;
  const u16* Bp = side2 ? Bt2 : Bt;

  const u16* Az = A + (size_t)kz * Klen;
  const u16* Bz = Bp + (size_t)kz * Klen;
  const int NT = Klen >> 6;

  const u16* src[LPW];
  const int swz = (((lane & 7) ^ (lane >> 3)) * 8);
#pragma unroll
  for (int i = 0; i < LPW; ++i) {
    const int c = wave * LPW + i;
    if (c < 16) src[i] = Az + (size_t)(bm * 128 + c * 8 + (lane >> 3)) * LDK + swz;
    else if (!DUAL || c < 16 + CH_B)
      src[i] = Bz + (size_t)(bnl * BN + (c - 16) * 8 + (lane >> 3)) * LDK + swz;
    else
      src[i] = Bt2 + (size_t)kz * Klen + (size_t)(bnl * BN + (c - 16 - CH_B) * 8 + (lane >> 3)) * LDK + swz;
  }
  const int dst0 = wave * LPW * 512 + lane * 8;

  auto STAGE = [&](int buf, int kt) {
    u16* base = smem + buf * TILE + dst0;
    const size_t ko = (size_t)kt * 64;
#pragma unroll
    for (int i = 0; i < LPW; ++i) gload_lds16(src[i] + ko, base + i * 512);
  };

  f32x4 acc[4][NFR];
  f32x4 acc2[DUAL ? 4 : 1][DUAL ? NFR : 1];
#pragma unroll
  for (int m = 0; m < 4; ++m)
#pragma unroll
    for (int n = 0; n < NFR; ++n) {
      acc[m][n] = f32x4{0.f, 0.f, 0.f, 0.f};
      if constexpr (DUAL) acc2[m][n] = f32x4{0.f, 0.f, 0.f, 0.f};
    }

  auto COMPUTE = [&](int buf) {
    const u16* Ab = smem + buf * TILE;
    const u16* Bb = Ab + 16 * 512;
    const u16* Ub = Ab + (16 + CH_B) * 512;
    bf16x8 a[2][4], b[2][NFR];
    bf16x8 u[DUAL ? 2 : 1][DUAL ? NFR : 1];
#pragma unroll
    for (int kk = 0; kk < 2; ++kk) {
      const int cc = kk * 4 + l16;
#pragma unroll
      for (int m = 0; m < 4; ++m) {
        const int rr = wr * 64 + m * 16 + l15;
        a[kk][m] = *(const bf16x8*)&Ab[rr * 64 + ((cc ^ (rr & 7)) * 8)];
      }
#pragma unroll
      for (int n = 0; n < NFR; ++n) {
        const int rr = wc * (BN / 4) + n * 16 + l15;
        b[kk][n] = *(const bf16x8*)&Bb[rr * 64 + ((cc ^ (rr & 7)) * 8)];
        if constexpr (DUAL)
          u[kk][n] = *(const bf16x8*)&Ub[rr * 64 + ((cc ^ (rr & 7)) * 8)];
      }
    }
    __builtin_amdgcn_s_setprio(1);
#pragma unroll
    for (int kk = 0; kk < 2; ++kk)
#pragma unroll
      for (int m = 0; m < 4; ++m)
#pragma unroll
        for (int n = 0; n < NFR; ++n)
          acc[m][n] = __builtin_amdgcn_mfma_f32_16x16x32_bf16(a[kk][m], b[kk][n], acc[m][n], 0, 0, 0);
    if constexpr (DUAL) {
#pragma unroll
      for (int kk = 0; kk < 2; ++kk)
#pragma unroll
        for (int m = 0; m < 4; ++m)
#pragma unroll
          for (int n = 0; n < NFR; ++n)
            acc2[m][n] = __builtin_amdgcn_mfma_f32_16x16x32_bf16(a[kk][m], u[kk][n], acc2[m][n], 0, 0, 0);
    }
    __builtin_amdgcn_s_setprio(0);
  };

  if constexpr (BUFS == 2) {
    STAGE(0, 0);
    wait_vmcnt<0>();
    __builtin_amdgcn_s_barrier();
    int cur = 0;
    for (int t = 0; t < NT; ++t) {
      if (t + 1 < NT) STAGE(cur ^ 1, t + 1);
      COMPUTE(cur);
      if (t + 1 < NT) { wait_vmcnt<0>(); __builtin_amdgcn_s_barrier(); }
      cur ^= 1;
    }
  } else {
    STAGE(0, 0);
    STAGE(1, 1);
    wait_vmcnt<LPW>();
    __builtin_amdgcn_s_barrier();
    int cur = 0;
    for (int t = 0; t < NT; ++t) {
      const int nb = (cur >= 1) ? cur - 1 : cur + 2;
      if (t + 2 < NT) STAGE(nb, t + 2);
      COMPUTE(cur);
      if (t + 1 < NT) {
        if (t + 2 < NT) wait_vmcnt<LPW>();
        else            wait_vmcnt<0>();
        __builtin_amdgcn_s_barrier();
      }
      cur = (cur == 2) ? 0 : cur + 1;
    }
  }

  const int row0 = bm * 128 + wr * 64 + l16 * 4;
  const int col0 = bnl * BN + wc * (BN / 4) + l15;
  float* Cf = (float*)(side2 ? Cv2 : Cv) + (size_t)kz * M * N;
  u16* Cb = (u16*)(side2 ? Cv2 : Cv) + (size_t)kz * M * N;
#pragma unroll
  for (int m = 0; m < 4; ++m)
#pragma unroll
    for (int n = 0; n < NFR; ++n)
#pragma unroll
      for (int rr = 0; rr < 4; ++rr) {
        const size_t idx = (size_t)(row0 + m * 16 + rr) * N + col0 + n * 16;
        if (MODE == 0) Cf[idx] = acc[m][n][rr];
        else if (MODE == 1) Cb[idx] = f2bf(acc[m][n][rr]);
        else if (MODE == 2) ((u16*)Cv)[idx] = f2bf(gelu_t(bf2f(gptr[idx])) * acc[m][n][rr]);
        else if (MODE == 4) {
          if constexpr (DUAL)
            ((u16*)Cv)[idx] = f2bf(gelu_t(acc[m][n][rr]) * acc2[m][n][rr]);
        }
      }
}

// ---------------- flash attention: 4-wave / 64 q-rows, LDS-staged KV -------
__global__ __launch_bounds__(256) void attn_kernel(
    const u16* __restrict__ qb, const u16* __restrict__ kt,
    const u16* __restrict__ vtile, const int* __restrict__ amask,
    u16* __restrict__ outp) {
  __shared__ __align__(16) u16 Ks[2][32 * 256];
  __shared__ __align__(16) u16 Vs[2][256 * 32];
  __shared__ __align__(16) u16 Ps[4][16 * 40];
  const int bid = blockIdx.x;
  const int qh = bid & 7;          // head = XCD
  const int qblk = bid >> 3;
  const int kvh = qh >> 1;
  const int q0 = qblk * 64;
  const int tid = threadIdx.x, lane = tid & 63, wave = tid >> 6;
  const int qrow = q0 + wave * 16;
  const int l15 = lane & 15, l16 = lane >> 4;

  bf16x8 qf[8];
  {
    const u16* qp = qb + (size_t)(qrow + l15) * (NHQ * HDIM) + qh * HDIM + l16 * 8;
#pragma unroll
    for (int kc = 0; kc < 8; ++kc) qf[kc] = *(const bf16x8*)(qp + kc * 32);
  }
  f32x4 acc[16];
#pragma unroll
  for (int n = 0; n < 16; ++n) acc[n] = f32x4{0.f, 0.f, 0.f, 0.f};
  float mr[4] = {-1e30f, -1e30f, -1e30f, -1e30f};
  float sr[4] = {0.f, 0.f, 0.f, 0.f};

  int lo = q0 - (SWIN - 1); if (lo < 0) lo = 0; lo &= ~31;
  const int ntiles = ((q0 + 63 - lo) >> 5) + 1;

  const char* kbase = (const char*)(kt + (size_t)kvh * S_LEN * HDIM);
  const char* vbase = (const char*)(vtile + (size_t)kvh * 64 * 256 * 32);

  auto STAGEKV = [&](int buf, int key0) {
    const char* ksrc = kbase + (size_t)key0 * 512;
    const char* vsrc = vbase + (size_t)(key0 >> 5) * 16384;
#pragma unroll
    for (int i = 0; i < 4; ++i) {
      const int b = (wave * 4 + i) * 1024 + lane * 16;
      gload_lds16(ksrc + (b ^ (((b >> 9) & 7) << 4)), (char*)&Ks[buf][0] + (wave * 4 + i) * 1024);
    }
#pragma unroll
    for (int i = 0; i < 4; ++i) {
      const int b = (wave * 4 + i) * 1024 + lane * 16;
      gload_lds16(vsrc + (b ^ (((b >> 6) & 3) << 4)), (char*)&Vs[buf][0] + (wave * 4 + i) * 1024);
    }
  };

  STAGEKV(0, lo);
  wait_vmcnt<0>();
  __builtin_amdgcn_s_barrier();

  int cur = 0;
  for (int it = 0; it < ntiles; ++it) {
    const int key0 = lo + it * 32;
    const int am0 = amask[key0 + l15];
    const int am1 = amask[key0 + 16 + l15];
    if (it + 1 < ntiles) { STAGEKV(cur ^ 1, key0 + 32); wait_vmcnt<8>(); }
    else                 { wait_vmcnt<0>(); }
    __builtin_amdgcn_s_barrier();

    if (key0 <= qrow + 15 && key0 + 31 >= qrow - (SWIN - 1)) {
      f32x4 sc[2];
      sc[0] = f32x4{0.f, 0.f, 0.f, 0.f};
      sc[1] = f32x4{0.f, 0.f, 0.f, 0.f};
#pragma unroll
      for (int ct = 0; ct < 2; ++ct) {
        const int r = ct * 16 + l15;
#pragma unroll
        for (int kc = 0; kc < 8; ++kc) {
          const int byte = (r * 512 + kc * 64 + l16 * 16) ^ ((r & 7) << 4);
          bf16x8 kf = *(const bf16x8*)((const char*)&Ks[cur][0] + byte);
          sc[ct] = __builtin_amdgcn_mfma_f32_16x16x32_bf16(qf[kc], kf, sc[ct], 0, 0, 0);
        }
      }
      float pr[2][4];
#pragma unroll
      for (int ct = 0; ct < 2; ++ct) {
        const int j = key0 + ct * 16 + l15;
        const bool jok = (ct ? am1 : am0) > 0;
#pragma unroll
        for (int r = 0; r < 4; ++r) {
          const int i = qrow + l16 * 4 + r;
          const bool ok = jok && (j <= i) && (i - j < SWIN);
          pr[ct][r] = ok ? sc[ct][r] * 0.0625f : -1e30f;
        }
      }
      float resc[4];
#pragma unroll
      for (int r = 0; r < 4; ++r) {
        float mx = fmaxf(pr[0][r], pr[1][r]);
#pragma unroll
        for (int mm = 1; mm < 16; mm <<= 1) mx = fmaxf(mx, __shfl_xor(mx, mm, 64));
        const float mnew = fmaxf(mr[r], mx);
        const float rs = __expf(mr[r] - mnew);
        mr[r] = mnew;
        float p0 = __expf(pr[0][r] - mnew);
        float p1 = __expf(pr[1][r] - mnew);
        pr[0][r] = p0; pr[1][r] = p1;
        float sm = p0 + p1;
#pragma unroll
        for (int mm = 1; mm < 16; mm <<= 1) sm += __shfl_xor(sm, mm, 64);
        sr[r] = sr[r] * rs + sm;
        resc[r] = rs;
      }
#pragma unroll
      for (int n = 0; n < 16; ++n)
#pragma unroll
        for (int r = 0; r < 4; ++r) acc[n][r] *= resc[r];
      u16* P = &Ps[wave][0];
#pragma unroll
      for (int ct = 0; ct < 2; ++ct)
#pragma unroll
        for (int r = 0; r < 4; ++r)
          P[(l16 * 4 + r) * 40 + ct * 16 + l15] = f2bf(pr[ct][r]);
      bf16x8 pa = *(const bf16x8*)&P[l15 * 40 + l16 * 8];
#pragma unroll
      for (int n = 0; n < 16; ++n) {
        const int d = n * 16 + l15;
        const int byte = (d * 64 + l16 * 16) ^ ((d & 3) << 4);
        bf16x8 vf = *(const bf16x8*)((const char*)&Vs[cur][0] + byte);
        acc[n] = __builtin_amdgcn_mfma_f32_16x16x32_bf16(pa, vf, acc[n], 0, 0, 0);
      }
    }
    __builtin_amdgcn_s_barrier();
    cur ^= 1;
  }
#pragma unroll
  for (int n = 0; n < 16; ++n)
#pragma unroll
    for (int r = 0; r < 4; ++r) {
      const int i = qrow + l16 * 4 + r;
      outp[(size_t)i * (NHQ * HDIM) + qh * HDIM + n * 16 + l15] = f2bf(acc[n][r] / sr[r]);
    }
}

// ---------------- gelu(tanh) * up (fallback path only) ----------------
__global__ void gelu_mul_kernel(const u16* __restrict__ g, const u16* __restrict__ u,
                                u16* __restrict__ o, int n8) {
  const int idx0 = blockIdx.x * blockDim.x + threadIdx.x;
  const int stride = gridDim.x * blockDim.x;
  for (int i = idx0; i < n8; i += stride) {
    uint4 gv = ((const uint4*)g)[i];
    uint4 uv = ((const uint4*)u)[i];
    u32 gg[4] = {gv.x, gv.y, gv.z, gv.w};
    u32 uu[4] = {uv.x, uv.y, uv.z, uv.w};
    u32 ow[4];
#pragma unroll
    for (int w = 0; w < 4; ++w) {
      float x0 = bf2f((u16)(gg[w] & 0xffff)), x1 = bf2f((u16)(gg[w] >> 16));
      float y0 = bf2f((u16)(uu[w] & 0xffff)), y1 = bf2f((u16)(uu[w] >> 16));
      ow[w] = (u32)f2bf(gelu_t(x0) * y0) | ((u32)f2bf(gelu_t(x1) * y1) << 16);
    }
    ((uint4*)o)[i] = make_uint4(ow[0], ow[1], ow[2], ow[3]);
  }
}

extern "C" void kernel_launch(void* const* d_in, const int* in_sizes, int n_in,
                              void* d_out, int out_size, void* d_ws, size_t ws_size,
                              hipStream_t stream) {
  const float* hidden = (const float*)d_in[0];
  const int*   amask  = (const int*)d_in[1];
  const int*   pos    = (const int*)d_in[2];
  const float* wq     = (const float*)d_in[3];
  const float* wk     = (const float*)d_in[4];
  const float* wv     = (const float*)d_in[5];
  const float* wo     = (const float*)d_in[6];
  const float* wg     = (const float*)d_in[7];
  const float* wu     = (const float*)d_in[8];
  const float* wd     = (const float*)d_in[9];
  const float* ln_in  = (const float*)d_in[10];
  const float* ln_pa  = (const float*)d_in[11];
  const float* ln_pf  = (const float*)d_in[12];
  const float* ln_po  = (const float*)d_in[13];
  float* out = (float*)d_out;

  char* ws = (char*)d_ws;
  size_t off = 0;
  auto alloc = [&](size_t b) { char* p = ws + off; off += (b + 255) & ~(size_t)255; return p; };
  u16*   WT    = (u16*)alloc((size_t)DFF * DMODEL * 2);
  u16*   hnorm = (u16*)alloc((size_t)S_LEN * DMODEL * 2);
  char*  big0  = alloc((size_t)S_LEN * DFF * 2);
  u16*   qb    = (u16*)alloc((size_t)S_LEN * NHQ * HDIM * 2);
  u16*   ktb   = (u16*)alloc((size_t)NHKV * S_LEN * HDIM * 2);
  u16*   vtile = (u16*)alloc((size_t)NHKV * 64 * 256 * 32 * 2);
  u16*   attn  = (u16*)alloc((size_t)S_LEN * NHQ * HDIM * 2);
  float* f32t  = (float*)alloc((size_t)S_LEN * DMODEL * 4);
  float* xres  = (float*)alloc((size_t)S_LEN * DMODEL * 4);
  u16*   gbuf  = (u16*)alloc((size_t)S_LEN * DFF * 2);
  u16*   ubuf  = (u16*)alloc((size_t)S_LEN * DFF * 2);
  u16*   WTU   = (u16*)alloc((size_t)DFF * DMODEL * 2);
  const bool fused_gu = (off <= ws_size);
  (void)n_in; (void)in_sizes; (void)out_size; (void)f32t; (void)ubuf;
  float* qkvf = (float*)big0;
  u16*   ggu  = (u16*)big0;
  u16*   opart = (u16*)big0;    // o-proj split-K4 bf16 partials (37.7MB = big0)
  u16*   part = gbuf;           // 8x bf16 down partials = exactly gbuf+ubuf
  const size_t PS = (size_t)S_LEN * DMODEL;
  (void)PS;

  const dim3 B256(256), B128(128), B512(512);

  // 1. h = rms(hidden, ln_in)
  rmsnorm_bf16_kernel<<<dim3(S_LEN), B256, 0, stream>>>(hidden, ln_in, hnorm);
  // 2. W_{q,k,v}^T  (merged into one launch; 32k x 128n float4 tiles)
  transpose_qkv_kernel<<<dim3(DMODEL / 32, 4096 / 128), B256, 0, stream>>>(wq, wk, wv, WT);
  // 3. qkv = h @ [wq|wk|wv]  (BN=128 2-buf: 64KB -> 2blk/CU, grid 512 = 1.0 round)
  gemm_pipe<128, 0, 2><<<dim3(512), B512, 0, stream>>>(hnorm, WT, WT, qkvf, qkvf, S_LEN, 4096, DMODEL, DMODEL, 32, 32, nullptr);
  // 4. RoPE (writes q + per-head-packed K)
  rope_kernel<<<dim3(S_LEN), B128, 0, stream>>>(qkvf, pos, qb, ktb);
  // 5. V tiles
  vpack_kernel<<<dim3(S_LEN / 32, HDIM / 32, NHKV), B256, 0, stream>>>(qkvf, vtile);
  // 6. attention (256 blocks x 4 waves, LDS-staged contiguous KV)
  attn_kernel<<<dim3((S_LEN / 64) * NHQ), B256, 0, stream>>>(qb, ktb, vtile, amask, attn);
  // 7. o partials = attn @ wo  (BN=192 2-buf split-K4 bf16 partials: grid 768
  //    = 1.5 rounds @2blk/CU; fixes the 0.75-round imbalance of grid 384)
  transpose_convert<<<dim3(2048 / 32, DMODEL / 128), B256, 0, stream>>>(wo, WT, 2048, DMODEL, DMODEL);
  gemm_pipe<192, 1, 2><<<dim3(768), B512, 0, stream>>>(attn, WT, WT, opart, opart, S_LEN, DMODEL, 512, 2048, 12, 12, nullptr);
  // 8+9. x = hidden + rms(sum of 4 bf16 o-partials); h2 = rms(x)  (fused)
  rms_add_rms_kernel<<<dim3(S_LEN), B256, 0, stream>>>(opart, ln_pa, hidden, ln_pf, xres, hnorm);
  if (fused_gu) {
    // 10+11. DUAL gate+up with in-register gelu: ggu = gelu(h@wg)*(h@wu)
    transpose_convert<<<dim3(DMODEL / 32, DFF / 128), B256, 0, stream>>>(wg, WT, DMODEL, DFF, DFF);
    transpose_convert<<<dim3(DMODEL / 32, DFF / 128), B256, 0, stream>>>(wu, WTU, DMODEL, DFF, DFF);
    gemm_pipe<192, 4, 2><<<dim3(768), B512, 0, stream>>>(hnorm, WT, WTU, ggu, nullptr, S_LEN, DFF, DMODEL, DMODEL, 48, 48, nullptr);
  } else {
    transpose_convert<<<dim3(DMODEL / 32, DFF / 128), B256, 0, stream>>>(wg, WT, DMODEL, DFF, DFF);
    gemm_pipe<192, 1, 3><<<dim3(768), B512, 0, stream>>>(hnorm, WT, WT, gbuf, gbuf, S_LEN, DFF, DMODEL, DMODEL, 48, 48, nullptr);
    transpose_convert<<<dim3(DMODEL / 32, DFF / 128), B256, 0, stream>>>(wu, WT, DMODEL, DFF, DFF);
    gemm_pipe<192, 2, 3><<<dim3(768), B512, 0, stream>>>(hnorm, WT, WT, ggu, ggu, S_LEN, DFF, DMODEL, DMODEL, 48, 48, gbuf);
  }
  // 12. ffn bf16 partials = ggu @ w_down (8-wave 2-buf, split-K=8: grid 1536)
  transpose_convert<<<dim3(DFF / 32, DMODEL / 128), B256, 0, stream>>>(wd, WT, DFF, DMODEL, DMODEL);
  gemm_pipe<192, 1, 2><<<dim3(1536), B512, 0, stream>>>(ggu, WT, WT, part, part, S_LEN, DMODEL, DFF / 8, DFF, 12, 12, nullptr);
  // 13. out = x + rms(sum of 8 bf16 partials)
  reduce8_rms_add_kernel<<<dim3(S_LEN), B256, 0, stream>>>(part, ln_po, xres, out);
}